// Round 7
// baseline (404.593 us; speedup 1.0000x reference)
//
#include <hip/hip_runtime.h>

// ReconPhongIF: Phong shading with ray-marched shadows.
// R10: 2-ray-per-lane ILP on R7's XCD-pinned per-block pools.
// R9 post-mortem: inter-block balance theory FALSIFIED - occupancy ~45% and
// VALUBusy ~42% are invariant across R6/R7/R9's structurally different
// mappings. The march is per-wave latency-bound: one serial chain per lane
// (step -> rcp/project -> 4 gathers -> lerp -> cmp), VALU duty per wave ~12%.
// R9 also regressed (151us, FETCH 3x) because 32-images-per-block blew L1;
// gather latency is on the chain -> revert to R7 mapping (one image/block,
// 2KB sliding window, 126us, FETCH 4MB).
// R10: each lane marches TWO independent rays in straight-line unconditional
// code: both slots' 8 gathers issue back-to-back -> ~2x VALU issue per
// 1x load latency -> per-wave duty ~doubles. Inactive slots compute masked
// garbage: index clamps moved to float domain before cvt (commutes exactly
// with int clamp for integral bounds -> active decisions bit-identical;
// garbage conversions stay defined), dead-slot state pinned to benign values.
// Ray decisions bit-identical to reference: sequential pos+=step fp32 adds,
// guarded rcp+Newton fast sample, exact-IEEE fallback inside the guard band.

#define SDIM 256
#define SS   (SDIM * SDIM)
#define TAN_T 0.08748866352592401      // tan(5 deg) in double
#define STEPC (2.0f / 255.0f)          // linspace(-1,1,256) step
#define POOL  1024                     // rays per block (4 rows)
#define CPB   64                       // chunks per batch (64*1024 = 65536)
#define MDV   (0.75f - 1e-6f)          // early-exit floor (depth >= 0.75 by input domain)

// ---------------- sample/test: fast path + guarded exact fallback ----------
// Safe for arbitrary (garbage) inputs: clamps applied in float before cvt.
// For active rays (pz > MDV, coords in range) identical to the reference
// sequence: float-clamp with integer bounds commutes with the int clamp.
__device__ __forceinline__ bool shadow_test(float px, float py, float pz,
                                            const float* __restrict__ im) {
#pragma clang fp contract(off)
    const float T = (float)TAN_T;
    const float K = (float)(128.0 / TAN_T);
    float inv = __builtin_amdgcn_rcpf(pz);
    inv = fmaf(fmaf(-pz, inv, 1.0f), inv, inv);
    const float xf = fmaf(px * inv, K, 127.5f);
    const float yf = fmaf(py * inv, K, 127.5f);
    const float x0ff = floorf(xf);
    const float y0ff = floorf(yf);
    const float wxf = xf - x0ff;
    const float wyf = yf - y0ff;
    const int x0c = (int)fminf(fmaxf(x0ff,        0.0f), 255.0f);
    const int x1c = (int)fminf(fmaxf(x0ff + 1.0f, 0.0f), 255.0f);
    const int y0c = (int)fminf(fmaxf(y0ff,        0.0f), 255.0f);
    const int y1c = (int)fminf(fmaxf(y0ff + 1.0f, 0.0f), 255.0f);
    const int r0 = y0c << 8, r1 = y1c << 8;
    const float v00 = im[r0 + x0c];
    const float v01 = im[r0 + x1c];
    const float v10 = im[r1 + x0c];
    const float v11 = im[r1 + x1c];
    const float omx = 1.0f - wxf, omy = 1.0f - wyf;
    const float t0 = fmaf(v01, wxf, v00 * omx);
    const float t1 = fmaf(v11, wxf, v10 * omx);
    const float sF = fmaf(t1, wyf, t0 * omy);
    const float diff = sF - pz;
    // guard: pos err ~3e-7*|coord|, Lipschitz ~0.5/px, 4x margin
    const float guard = fmaf(fabsf(xf) + fabsf(yf), 6e-7f, 1e-5f);
    bool shf = diff < 0.0f;
    if (__builtin_expect(fabsf(diff) <= guard, 0)) {
        // exact fallback: bit-identical to reference for active rays
        const float gx = (px / pz) / T;
        const float gy = (py / pz) / T;
        const float x = (gx + 1.0f) * 128.0f - 0.5f;
        const float y = (gy + 1.0f) * 128.0f - 0.5f;
        const float xo = floorf(x), yo = floorf(y);
        const float wx = x - xo, wy = y - yo;
        const int ex0c = (int)fminf(fmaxf(xo,        0.0f), 255.0f);
        const int ex1c = (int)fminf(fmaxf(xo + 1.0f, 0.0f), 255.0f);
        const int ey0c = (int)fminf(fmaxf(yo,        0.0f), 255.0f);
        const int ey1c = (int)fminf(fmaxf(yo + 1.0f, 0.0f), 255.0f);
        const float e00 = im[(ey0c << 8) + ex0c];
        const float e01 = im[(ey0c << 8) + ex1c];
        const float e10 = im[(ey1c << 8) + ex0c];
        const float e11 = im[(ey1c << 8) + ex1c];
        float s = e00 * (1.0f - wx) * (1.0f - wy);
        s = s + e01 * wx * (1.0f - wy);
        s = s + e10 * (1.0f - wx) * wy;
        s = s + e11 * wx * wy;
        shf = (s - pz) < 0.0f;
    }
    return shf;
}

// refill one slot from the block pool (sequential pop order, wave-cooperative)
#define REFILL(has, px, py, pz, rr, krem)                                      \
    do {                                                                       \
        const bool need = (!has) && (!done);                                   \
        const unsigned long long mneed = __ballot(need);                       \
        if (mneed != 0ull) {                                                   \
            const int leader = (int)__ffsll(mneed) - 1;                        \
            int base = 0;                                                      \
            if (lane == leader) base = atomicAdd(&popc, __popcll(mneed));      \
            base = __shfl(base, leader, 64);                                   \
            if (need) {                                                        \
                const int p = base +                                           \
                    (int)__popcll(mneed & ((1ull << (unsigned)lane) - 1ull));  \
                if (p < POOL) {                                                \
                    const float d = dcache[p];                                 \
                    const int gidx = rbase + p;                                \
                    const int i = gidx >> 8, j = gidx & 255;                   \
                    const float cj = (-1.0f + (float)j * STEPC) * T;           \
                    const float ci = (-1.0f + (float)i * STEPC) * T;           \
                    px = cj * d; py = ci * d; pz = d;                          \
                    rr = p; krem = 256; has = true;                            \
                } else {                                                       \
                    done = true;                                               \
                }                                                              \
            }                                                                  \
        }                                                                      \
    } while (0)

// ---------------- stage 1: persistent-pool ray march, ILP=2 ----------------
__global__ __launch_bounds__(256) void shadow_march(const float* __restrict__ depth,
                                                    const float* __restrict__ light,
                                                    unsigned char* __restrict__ shmap) {
#pragma clang fp contract(off)
    // XCD-aware decode (validated R7: FETCH 47.5->4.1 MB): blk&7 -> XCD,
    // each XCD owns a contiguous group of 4 batches (1 MiB, L2-resident).
    const int blk   = blockIdx.x;
    const int xcd   = blk & 7;
    const int idx   = blk >> 3;            // 0..255 within XCD
    const int b     = (xcd << 2) | (idx >> 6);   // batch: 4 per XCD
    const int chunk = idx & (CPB - 1);     // chunk within batch
    const int rbase = chunk * POOL;        // ray offset within batch (4 rows)
    const float* im = depth + (size_t)b * SS;
    const int tid = threadIdx.x;
    const int lane = tid & 63;

    // per-batch params (uniform; exact reference op order)
    const float lx = light[b * 2 + 0];
    const float ly = light[b * 2 + 1];
    float n2 = lx * lx;
    n2 = n2 + ly * ly;
    n2 = n2 + 1.0f;
    const float nr = sqrtf(n2);
    const float sx = (-(lx / nr)) / 256.0f;
    const float sy = (-(ly / nr)) / 256.0f;
    const float sz = (-(1.0f / nr)) / 256.0f;
    const float T = (float)TAN_T;

    __shared__ float         dcache[POOL];
    __shared__ unsigned char res[POOL];
    __shared__ int           popc;
    if (tid == 0) popc = 0;
#pragma unroll
    for (int u = 0; u < POOL / 256; ++u) {
        const int r = tid + u * 256;
        dcache[r] = im[rbase + r];         // coalesced
    }
    __syncthreads();

    // ---- two independent ray slots per lane ----
    bool hasA = false, hasB = false, done = false;
    float pxA = 0.0f, pyA = 0.0f, pzA = 1.0f;
    float pxB = 0.0f, pyB = 0.0f, pzB = 1.0f;
    int rrA = 0, krA = 0, rrB = 0, krB = 0;

#pragma unroll 1
    while (true) {
        REFILL(hasA, pxA, pyA, pzA, rrA, krA);
        REFILL(hasB, pxB, pyB, pzB, rrB, krB);
        if (__ballot(hasA || hasB) == 0ull) break;

        // unconditional double-step: both chains in straight-line code so the
        // 8 gathers issue together (one latency window per iteration)
        pxA += sx; pyA += sy; pzA += sz; --krA;
        pxB += sx; pyB += sy; pzB += sz; --krB;
        const bool hitA = shadow_test(pxA, pyA, pzA, im);
        const bool hitB = shadow_test(pxB, pyB, pzB, im);

        if (hasA) {
            const bool fl = pzA <= MDV;          // exact early-exit floor
            if (fl || hitA || krA == 0) {
                res[rrA] = (!fl && hitA) ? (unsigned char)1 : (unsigned char)0;
                hasA = false;
                pxA = 0.0f; pyA = 0.0f; pzA = 1.0f;   // benign dead-slot state
            }
        }
        if (hasB) {
            const bool fl = pzB <= MDV;
            if (fl || hitB || krB == 0) {
                res[rrB] = (!fl && hitB) ? (unsigned char)1 : (unsigned char)0;
                hasB = false;
                pxB = 0.0f; pyB = 0.0f; pzB = 1.0f;
            }
        }
    }
    __syncthreads();
    // coalesced flush: 1024 result bytes = 256 dwords
    ((unsigned int*)(shmap + (size_t)b * SS + rbase))[tid] = ((const unsigned int*)res)[tid];
}

// ---------------- stage 2: blur + Phong composition ----------------
__device__ __constant__ float W1[7] = {
    0.07015933f, 0.13107488f, 0.19071282f, 0.21610594f,
    0.19071282f, 0.13107488f, 0.07015933f
};

__device__ __forceinline__ float fpow(float x, float p) {
    return __builtin_amdgcn_exp2f(p * __builtin_amdgcn_logf(x));
}
__device__ __forceinline__ float ftanh(float x) {
    const float e = __builtin_amdgcn_exp2f(x * 2.8853900817779268f);
    return (e - 1.0f) * __builtin_amdgcn_rcpf(e + 1.0f);
}

__global__ __launch_bounds__(256) void compose_kernel(const float* __restrict__ netA,
                                                      const float* __restrict__ netL,
                                                      const float* __restrict__ nrm,
                                                      const float* __restrict__ light,
                                                      const unsigned char* __restrict__ shmap,
                                                      float* __restrict__ out) {
    __shared__ float tile[22][23];

    const int b  = blockIdx.z;
    const int tx = threadIdx.x & 15;
    const int ty = threadIdx.x >> 4;
    const int j0 = blockIdx.x * 16;
    const int i0 = blockIdx.y * 16;

    const unsigned char* shb = shmap + (size_t)b * SS;
    for (int idx = threadIdx.x; idx < 22 * 22; idx += 256) {
        const int r = idx / 22, c = idx - r * 22;
        const int gi = i0 - 3 + r, gj = j0 - 3 + c;
        float v = 0.0f;
        if (gi >= 0 && gi < SDIM && gj >= 0 && gj < SDIM) v = (float)shb[gi * SDIM + gj];
        tile[r][c] = v;
    }
    __syncthreads();

    const int i = i0 + ty;
    const int j = j0 + tx;

    float shadow_s = 0.0f;
#pragma unroll
    for (int dy = 0; dy < 7; ++dy) {
        float rs = 0.0f;
#pragma unroll
        for (int dx = 0; dx < 7; ++dx) rs += W1[dx] * tile[ty + dy][tx + dx];
        shadow_s += W1[dy] * rs;
    }

    const float l0 = tanhf(netL[b * 6 + 0]);
    const float l1 = tanhf(netL[b * 6 + 1]);
    const float l2 = tanhf(netL[b * 6 + 2]);
    const float l5 = tanhf(netL[b * 6 + 5]);
    const float e  = l0 * 0.5f + 0.5f;
    const float f  = e * (float)10.313708498984761 + 1.0f;
    const float spec_alpha    = f * f;
    const float spec_strength = (l5 * 0.5f + 0.5f) * 0.5f;
    const float light_a = l1 / 2.0f + 0.5f;
    const float light_b = l2 / 2.0f + 0.5f;

    const float lx = light[b * 2 + 0];
    const float ly = light[b * 2 + 1];
    const float ln = sqrtf(lx * lx + ly * ly + 1.0f);
    const float ldx = lx / ln, ldy = ly / ln, ldz = 1.0f / ln;

    const float T = (float)TAN_T;
    const float xsj = (-1.0f + (float)(SDIM - 1 - j) * STEPC) * T;
    const float xsi = (-1.0f + (float)(SDIM - 1 - i) * STEPC) * T;
    const float vn = sqrtf(xsj * xsj + xsi * xsi + 1.0f);
    const float vd0 = xsj / vn, vd1 = xsi / vn, vd2 = 1.0f / vn;

    const size_t pix = (size_t)i * SDIM + j;
    const float n0 = nrm[((size_t)(b * 3 + 0)) * SS + pix];
    const float n1 = nrm[((size_t)(b * 3 + 1)) * SS + pix];
    const float n2 = nrm[((size_t)(b * 3 + 2)) * SS + pix];

    const float cos_t   = n0 * ldx + n1 * ldy + n2 * ldz;
    const float diffuse = fmaxf(cos_t, 0.0f);

    const float r0 = 2.0f * cos_t * n0 - ldx;
    const float r1 = 2.0f * cos_t * n1 - ldy;
    const float r2 = 2.0f * cos_t * n2 - ldz;
    float spec = fmaxf(vd0 * r0 + vd1 * r1 + vd2 * r2, 0.0f);
    const float gate  = (cos_t > 0.0f) ? 1.0f : 0.0f;
    const float maskv = (i >= 5 && i < SDIM - 5 && j >= 5 && j < SDIM - 5) ? 1.0f : 0.0f;
    spec = spec * gate * maskv;
    const float sclip = fminf(fmaxf(spec, 1e-7f), (float)(1.0 - 1e-7));
    const float sshad = fpow(sclip, spec_alpha);

    const float shadow_factor = fminf(fmaxf(1.0f - shadow_s, 0.1f), 1.0f);
    const float shading   = light_a + light_b * diffuse * shadow_factor;
    const float spec_term = spec_strength * light_b * sshad;

    const float inv_g = (float)(1.0 / 2.2);
#pragma unroll
    for (int c = 0; c < 3; ++c) {
        const float a   = netA[((size_t)(b * 5 + c)) * SS + pix];
        const float alb = fpow(ftanh(a) * 0.5f + 0.5f, 2.2f);
        float rim = alb * shading + spec_term;
        rim = fmaxf(rim, 1e-7f);
        out[((size_t)(b * 3 + c)) * SS + pix] = fpow(rim, inv_g);
    }
}

extern "C" void kernel_launch(void* const* d_in, const int* in_sizes, int n_in,
                              void* d_out, int out_size, void* d_ws, size_t ws_size,
                              hipStream_t stream) {
    const float* netA  = (const float*)d_in[0];
    const float* netL  = (const float*)d_in[1];
    const float* nrm   = (const float*)d_in[2];
    const float* depth = (const float*)d_in[3];
    const float* light = (const float*)d_in[4];
    float* out = (float*)d_out;

    unsigned char* shmap = (unsigned char*)d_ws;   // 2 MiB

    shadow_march<<<32 * CPB, 256, 0, stream>>>(depth, light, shmap);
    compose_kernel<<<dim3(SDIM / 16, SDIM / 16, 32), 256, 0, stream>>>(netA, netL, nrm,
                                                                       light, shmap, out);
}

// Round 9
// 217.866 us; speedup vs baseline: 1.8571x; 1.8571x over previous
//
#include <hip/hip_runtime.h>

// ReconPhongIF: Phong shading with ray-marched shadows.
// R11: scalar per-wave pool cursor + same-ray unroll-2 fused dual test.
// R10 post-mortem: dual-slot ILP doubled VALU work (VALU-equiv 53->100us)
// with ZERO overlap - shadow_test's guard branch sits between slot A's and
// slot B's loads, serializing the two chains; dual REFILL (2 ballots + LDS
// atomic + ds_bpermute) doubled per-iteration LDS stalls. 300us regression.
// R11 fixes both on the 126us R7 base:
//  (1) static per-wave pool quarters (256 rays = 1 image row per wave):
//      pop cursor is wave-uniform by construction (cursor += popc(ballot)),
//      killing the LDS atomic + shfl from the per-iteration critical path;
//  (2) unroll-2 on the SAME ray: both steps' 8 gather addresses computed
//      before any load -> one latency window; rare exact-fallback branch
//      hoisted after both fast paths; <=1 wasted step per ray.
// R7 XCD-pinned one-image-per-block mapping kept (FETCH 4MB, L1-resident).
// (R11 resubmission: previous round failed with GPUAcquisitionTimeout.)
// Ray decisions bit-identical to reference: sequential pos+=step fp32 adds
// (px1=px+sx; px2=px1+sx), guarded rcp+Newton fast sample, exact-IEEE
// fallback inside the guard band; float-domain clamps commute with the
// reference int clamps for all reachable coords.

#define SDIM 256
#define SS   (SDIM * SDIM)
#define TAN_T 0.08748866352592401      // tan(5 deg) in double
#define STEPC (2.0f / 255.0f)          // linspace(-1,1,256) step
#define POOL  1024                     // rays per block (4 rows)
#define WPOOL 256                      // rays per wave (1 row)
#define CPB   64                       // chunks per batch (64*1024 = 65536)
#define MDV   (0.75f - 1e-6f)          // early-exit floor (depth >= 0.75 by input domain)

// ---------------- exact fallback: bit-identical to reference ---------------
__device__ __forceinline__ bool shadow_exact(float px, float py, float pz,
                                             const float* __restrict__ im) {
#pragma clang fp contract(off)
    const float T = (float)TAN_T;
    const float gx = (px / pz) / T;
    const float gy = (py / pz) / T;
    const float x = (gx + 1.0f) * 128.0f - 0.5f;
    const float y = (gy + 1.0f) * 128.0f - 0.5f;
    const float xo = floorf(x), yo = floorf(y);
    const float wx = x - xo, wy = y - yo;
    const int ex0c = (int)fminf(fmaxf(xo,        0.0f), 255.0f);
    const int ex1c = (int)fminf(fmaxf(xo + 1.0f, 0.0f), 255.0f);
    const int ey0c = (int)fminf(fmaxf(yo,        0.0f), 255.0f);
    const int ey1c = (int)fminf(fmaxf(yo + 1.0f, 0.0f), 255.0f);
    const float e00 = im[(ey0c << 8) + ex0c];
    const float e01 = im[(ey0c << 8) + ex1c];
    const float e10 = im[(ey1c << 8) + ex0c];
    const float e11 = im[(ey1c << 8) + ex1c];
    float s = e00 * (1.0f - wx) * (1.0f - wy);
    s = s + e01 * wx * (1.0f - wy);
    s = s + e10 * (1.0f - wx) * wy;
    s = s + e11 * wx * wy;
    return (s - pz) < 0.0f;
}

// -------- dual-step fast test: 8 gathers in one window, fallback after -----
__device__ __forceinline__ void shadow_test2(float px1, float py1, float pz1,
                                             float px2, float py2, float pz2,
                                             const float* __restrict__ im,
                                             bool& h1, bool& h2) {
#pragma clang fp contract(off)
    const float K = (float)(128.0 / TAN_T);
    float inv1 = __builtin_amdgcn_rcpf(pz1);
    inv1 = fmaf(fmaf(-pz1, inv1, 1.0f), inv1, inv1);
    float inv2 = __builtin_amdgcn_rcpf(pz2);
    inv2 = fmaf(fmaf(-pz2, inv2, 1.0f), inv2, inv2);
    const float xf1 = fmaf(px1 * inv1, K, 127.5f);
    const float yf1 = fmaf(py1 * inv1, K, 127.5f);
    const float xf2 = fmaf(px2 * inv2, K, 127.5f);
    const float yf2 = fmaf(py2 * inv2, K, 127.5f);
    const float x0f1 = floorf(xf1), y0f1 = floorf(yf1);
    const float x0f2 = floorf(xf2), y0f2 = floorf(yf2);
    const float wx1 = xf1 - x0f1, wy1 = yf1 - y0f1;
    const float wx2 = xf2 - x0f2, wy2 = yf2 - y0f2;
    // float-domain clamps (commute with reference int clamp; garbage-safe)
    const int x0c1 = (int)fminf(fmaxf(x0f1,        0.0f), 255.0f);
    const int x1c1 = (int)fminf(fmaxf(x0f1 + 1.0f, 0.0f), 255.0f);
    const int y0c1 = (int)fminf(fmaxf(y0f1,        0.0f), 255.0f);
    const int y1c1 = (int)fminf(fmaxf(y0f1 + 1.0f, 0.0f), 255.0f);
    const int x0c2 = (int)fminf(fmaxf(x0f2,        0.0f), 255.0f);
    const int x1c2 = (int)fminf(fmaxf(x0f2 + 1.0f, 0.0f), 255.0f);
    const int y0c2 = (int)fminf(fmaxf(y0f2,        0.0f), 255.0f);
    const int y1c2 = (int)fminf(fmaxf(y0f2 + 1.0f, 0.0f), 255.0f);
    const int r01 = y0c1 << 8, r11 = y1c1 << 8;
    const int r02 = y0c2 << 8, r12 = y1c2 << 8;
    // all 8 loads issued back-to-back: one latency window
    const float a00 = im[r01 + x0c1];
    const float a01 = im[r01 + x1c1];
    const float a10 = im[r11 + x0c1];
    const float a11 = im[r11 + x1c1];
    const float b00 = im[r02 + x0c2];
    const float b01 = im[r02 + x1c2];
    const float b10 = im[r12 + x0c2];
    const float b11 = im[r12 + x1c2];
    const float omx1 = 1.0f - wx1, omy1 = 1.0f - wy1;
    const float omx2 = 1.0f - wx2, omy2 = 1.0f - wy2;
    const float t0a = fmaf(a01, wx1, a00 * omx1);
    const float t1a = fmaf(a11, wx1, a10 * omx1);
    const float sa  = fmaf(t1a, wy1, t0a * omy1);
    const float t0b = fmaf(b01, wx2, b00 * omx2);
    const float t1b = fmaf(b11, wx2, b10 * omx2);
    const float sb  = fmaf(t1b, wy2, t0b * omy2);
    const float d1 = sa - pz1;
    const float d2 = sb - pz2;
    // guard: pos err ~3e-7*|coord|, Lipschitz ~0.5/px, 4x margin
    const float g1 = fmaf(fabsf(xf1) + fabsf(yf1), 6e-7f, 1e-5f);
    const float g2 = fmaf(fabsf(xf2) + fabsf(yf2), 6e-7f, 1e-5f);
    h1 = d1 < 0.0f;
    h2 = d2 < 0.0f;
    const bool amb1 = fabsf(d1) <= g1;
    const bool amb2 = fabsf(d2) <= g2;
    if (__builtin_expect(amb1 || amb2, 0)) {
        if (amb1) h1 = shadow_exact(px1, py1, pz1, im);
        if (amb2) h2 = shadow_exact(px2, py2, pz2, im);
    }
}

// ---------------- stage 1: persistent march, wave-local pools --------------
__global__ __launch_bounds__(256) void shadow_march(const float* __restrict__ depth,
                                                    const float* __restrict__ light,
                                                    unsigned char* __restrict__ shmap) {
#pragma clang fp contract(off)
    // XCD-aware decode (validated R7: FETCH 47.5->4.1 MB): blk&7 -> XCD,
    // each XCD owns a contiguous group of 4 batches (1 MiB, L2-resident).
    const int blk   = blockIdx.x;
    const int xcd   = blk & 7;
    const int idx   = blk >> 3;            // 0..255 within XCD
    const int b     = (xcd << 2) | (idx >> 6);   // batch: 4 per XCD
    const int chunk = idx & (CPB - 1);     // chunk within batch
    const int rbase = chunk * POOL;        // ray offset within batch (4 rows)
    const float* im = depth + (size_t)b * SS;
    const int tid  = threadIdx.x;
    const int lane = tid & 63;
    const int wv   = tid >> 6;

    // per-batch params (uniform; exact reference op order)
    const float lx = light[b * 2 + 0];
    const float ly = light[b * 2 + 1];
    float n2 = lx * lx;
    n2 = n2 + ly * ly;
    n2 = n2 + 1.0f;
    const float nr = sqrtf(n2);
    const float sx = (-(lx / nr)) / 256.0f;
    const float sy = (-(ly / nr)) / 256.0f;
    const float sz = (-(1.0f / nr)) / 256.0f;
    const float T = (float)TAN_T;

    __shared__ float         dcache[POOL];
    __shared__ unsigned char res[POOL];
#pragma unroll
    for (int u = 0; u < POOL / 256; ++u) {
        const int r = tid + u * 256;
        dcache[r] = im[rbase + r];         // coalesced
    }
    __syncthreads();

    // ---- wave-local sequential pop (cursor is wave-uniform: no atomics) ----
    const int wbase = wv << 8;             // this wave's 256-ray quarter (1 row)
    int cursor = 0;                        // uniform across the wave
    bool has = false, done = false;
    float px = 0.0f, py = 0.0f, pz = 1.0f;
    int rr = 0, krem = 0;

#pragma unroll 1
    while (true) {
        const bool need = (!has) && (!done);
        const unsigned long long mneed = __ballot(need);
        if (mneed != 0ull) {               // wave-uniform branch
            if (need) {
                const int prefix = (int)__popcll(mneed & ((1ull << (unsigned)lane) - 1ull));
                const int p = cursor + prefix;
                if (p < WPOOL) {
                    const int q = wbase + p;
                    const float d = dcache[q];
                    const int gidx = rbase + q;
                    const int i = gidx >> 8, j = gidx & 255;
                    const float cj = (-1.0f + (float)j * STEPC) * T;
                    const float ci = (-1.0f + (float)i * STEPC) * T;
                    px = cj * d; py = ci * d; pz = d;
                    rr = q; krem = 256; has = true;
                } else {
                    done = true;
                }
            }
            cursor += (int)__popcll(mneed);   // uniform update, all lanes
        }
        if (__ballot(has) == 0ull) break;
        if (has) {
            // two sequential steps (bit-exact chain), tested together
            const float px1 = px + sx, py1 = py + sy, pz1 = pz + sz;
            const float px2 = px1 + sx, py2 = py1 + sy, pz2 = pz1 + sz;
            bool h1, h2;
            shadow_test2(px1, py1, pz1, px2, py2, pz2, im, h1, h2);
            const bool fl1 = pz1 <= MDV;   // exact early-exit floor
            const bool fl2 = pz2 <= MDV;
            krem -= 2;
            bool dead = true;
            unsigned char rv = 0;
            if      (fl1)       { rv = 0; }
            else if (h1)        { rv = 1; }
            else if (fl2)       { rv = 0; }
            else if (h2)        { rv = 1; }
            else if (krem == 0) { rv = 0; }
            else dead = false;
            if (dead) {
                res[rr] = rv;
                has = false;
                px = 0.0f; py = 0.0f; pz = 1.0f;   // benign dead-lane state
            } else {
                px = px2; py = py2; pz = pz2;
            }
        }
    }
    __syncthreads();
    // coalesced flush: 1024 result bytes = 256 dwords
    ((unsigned int*)(shmap + (size_t)b * SS + rbase))[tid] = ((const unsigned int*)res)[tid];
}

// ---------------- stage 2: blur + Phong composition ----------------
__device__ __constant__ float W1[7] = {
    0.07015933f, 0.13107488f, 0.19071282f, 0.21610594f,
    0.19071282f, 0.13107488f, 0.07015933f
};

__device__ __forceinline__ float fpow(float x, float p) {
    return __builtin_amdgcn_exp2f(p * __builtin_amdgcn_logf(x));
}
__device__ __forceinline__ float ftanh(float x) {
    const float e = __builtin_amdgcn_exp2f(x * 2.8853900817779268f);
    return (e - 1.0f) * __builtin_amdgcn_rcpf(e + 1.0f);
}

__global__ __launch_bounds__(256) void compose_kernel(const float* __restrict__ netA,
                                                      const float* __restrict__ netL,
                                                      const float* __restrict__ nrm,
                                                      const float* __restrict__ light,
                                                      const unsigned char* __restrict__ shmap,
                                                      float* __restrict__ out) {
    __shared__ float tile[22][23];

    const int b  = blockIdx.z;
    const int tx = threadIdx.x & 15;
    const int ty = threadIdx.x >> 4;
    const int j0 = blockIdx.x * 16;
    const int i0 = blockIdx.y * 16;

    const unsigned char* shb = shmap + (size_t)b * SS;
    for (int idx = threadIdx.x; idx < 22 * 22; idx += 256) {
        const int r = idx / 22, c = idx - r * 22;
        const int gi = i0 - 3 + r, gj = j0 - 3 + c;
        float v = 0.0f;
        if (gi >= 0 && gi < SDIM && gj >= 0 && gj < SDIM) v = (float)shb[gi * SDIM + gj];
        tile[r][c] = v;
    }
    __syncthreads();

    const int i = i0 + ty;
    const int j = j0 + tx;

    float shadow_s = 0.0f;
#pragma unroll
    for (int dy = 0; dy < 7; ++dy) {
        float rs = 0.0f;
#pragma unroll
        for (int dx = 0; dx < 7; ++dx) rs += W1[dx] * tile[ty + dy][tx + dx];
        shadow_s += W1[dy] * rs;
    }

    const float l0 = tanhf(netL[b * 6 + 0]);
    const float l1 = tanhf(netL[b * 6 + 1]);
    const float l2 = tanhf(netL[b * 6 + 2]);
    const float l5 = tanhf(netL[b * 6 + 5]);
    const float e  = l0 * 0.5f + 0.5f;
    const float f  = e * (float)10.313708498984761 + 1.0f;
    const float spec_alpha    = f * f;
    const float spec_strength = (l5 * 0.5f + 0.5f) * 0.5f;
    const float light_a = l1 / 2.0f + 0.5f;
    const float light_b = l2 / 2.0f + 0.5f;

    const float lx = light[b * 2 + 0];
    const float ly = light[b * 2 + 1];
    const float ln = sqrtf(lx * lx + ly * ly + 1.0f);
    const float ldx = lx / ln, ldy = ly / ln, ldz = 1.0f / ln;

    const float T = (float)TAN_T;
    const float xsj = (-1.0f + (float)(SDIM - 1 - j) * STEPC) * T;
    const float xsi = (-1.0f + (float)(SDIM - 1 - i) * STEPC) * T;
    const float vn = sqrtf(xsj * xsj + xsi * xsi + 1.0f);
    const float vd0 = xsj / vn, vd1 = xsi / vn, vd2 = 1.0f / vn;

    const size_t pix = (size_t)i * SDIM + j;
    const float n0 = nrm[((size_t)(b * 3 + 0)) * SS + pix];
    const float n1 = nrm[((size_t)(b * 3 + 1)) * SS + pix];
    const float n2 = nrm[((size_t)(b * 3 + 2)) * SS + pix];

    const float cos_t   = n0 * ldx + n1 * ldy + n2 * ldz;
    const float diffuse = fmaxf(cos_t, 0.0f);

    const float r0 = 2.0f * cos_t * n0 - ldx;
    const float r1 = 2.0f * cos_t * n1 - ldy;
    const float r2 = 2.0f * cos_t * n2 - ldz;
    float spec = fmaxf(vd0 * r0 + vd1 * r1 + vd2 * r2, 0.0f);
    const float gate  = (cos_t > 0.0f) ? 1.0f : 0.0f;
    const float maskv = (i >= 5 && i < SDIM - 5 && j >= 5 && j < SDIM - 5) ? 1.0f : 0.0f;
    spec = spec * gate * maskv;
    const float sclip = fminf(fmaxf(spec, 1e-7f), (float)(1.0 - 1e-7));
    const float sshad = fpow(sclip, spec_alpha);

    const float shadow_factor = fminf(fmaxf(1.0f - shadow_s, 0.1f), 1.0f);
    const float shading   = light_a + light_b * diffuse * shadow_factor;
    const float spec_term = spec_strength * light_b * sshad;

    const float inv_g = (float)(1.0 / 2.2);
#pragma unroll
    for (int c = 0; c < 3; ++c) {
        const float a   = netA[((size_t)(b * 5 + c)) * SS + pix];
        const float alb = fpow(ftanh(a) * 0.5f + 0.5f, 2.2f);
        float rim = alb * shading + spec_term;
        rim = fmaxf(rim, 1e-7f);
        out[((size_t)(b * 3 + c)) * SS + pix] = fpow(rim, inv_g);
    }
}

extern "C" void kernel_launch(void* const* d_in, const int* in_sizes, int n_in,
                              void* d_out, int out_size, void* d_ws, size_t ws_size,
                              hipStream_t stream) {
    const float* netA  = (const float*)d_in[0];
    const float* netL  = (const float*)d_in[1];
    const float* nrm   = (const float*)d_in[2];
    const float* depth = (const float*)d_in[3];
    const float* light = (const float*)d_in[4];
    float* out = (float*)d_out;

    unsigned char* shmap = (unsigned char*)d_ws;   // 2 MiB

    shadow_march<<<32 * CPB, 256, 0, stream>>>(depth, light, shmap);
    compose_kernel<<<dim3(SDIM / 16, SDIM / 16, 32), 256, 0, stream>>>(netA, netL, nrm,
                                                                       light, shmap, out);
}